// Round 8
// baseline (229.407 us; speedup 1.0000x reference)
//
#include <hip/hip_runtime.h>
#include <hip/hip_bf16.h>

// Problem dims (fixed by setup_inputs)
#define BB 8
#define SS 2048
#define DD 1024
#define DKK 128

using bf16x8  = __attribute__((ext_vector_type(8))) __bf16;
using floatx4 = __attribute__((ext_vector_type(4))) float;
using intx4   = __attribute__((ext_vector_type(4))) int;

// async global->LDS, 16B/lane. LDS dest = wave-uniform base + lane*16 (HW rule).
__device__ __forceinline__ void lds16(const void* g, void* l) {
    __builtin_amdgcn_global_load_lds((const __attribute__((address_space(1))) void*)g,
                                     (__attribute__((address_space(3))) void*)l, 16, 0, 0);
}

__device__ __forceinline__ int pack2(float a, float b) {
    union { __bf16 h; unsigned short u; } ua, ub;
    ua.h = (__bf16)a; ub.h = (__bf16)b;
    return (int)(ua.u | ((unsigned)ub.u << 16));
}

// ---------------------------------------------------------------------------
// Kernel 0: W (fp32 [128][1024]) -> bf16, k-tile-major + 16B-block XOR swizzle
// ---------------------------------------------------------------------------
__global__ __launch_bounds__(256) void convw_kernel(
    const float* __restrict__ Wq, const float* __restrict__ Wk,
    const float* __restrict__ Wv, __bf16* __restrict__ Wt)
{
    const int z = blockIdx.y;
    const float* W = (z == 0) ? Wq : (z == 1) ? Wk : Wv;
    const int t  = blockIdx.x * 256 + threadIdx.x;   // 0..16383
    const int n  = t >> 7;
    const int k0 = (t & 127) * 8;
    float4 f0 = *(const float4*)(W + n * DD + k0);
    float4 f1 = *(const float4*)(W + n * DD + k0 + 4);
    bf16x8 v;
    v[0]=(__bf16)f0.x; v[1]=(__bf16)f0.y; v[2]=(__bf16)f0.z; v[3]=(__bf16)f0.w;
    v[4]=(__bf16)f1.x; v[5]=(__bf16)f1.y; v[6]=(__bf16)f1.z; v[7]=(__bf16)f1.w;
    const int kb  = (k0 >> 3) & 7;
    const int kbs = kb ^ (n & 7);
    *(bf16x8*)(Wt + (size_t)z * 131072 + ((k0 >> 6) * 128 + n) * 64 + kbs * 8) = v;
}

// ---------------------------------------------------------------------------
// Kernel 1: projections (unchanged from R6 — conflict-free W reg-staging).
// ---------------------------------------------------------------------------
__global__ __launch_bounds__(256) void proj_kernel(
    const float* __restrict__ x, const float* __restrict__ ctx,
    const __bf16* __restrict__ Wt, const int* __restrict__ lengths,
    __bf16* __restrict__ Qb, __bf16* __restrict__ Kb, __bf16* __restrict__ Vt)
{
    __shared__ __align__(16) __bf16 SH[20992];      // 41984 B
    __bf16* Abuf = SH;                              // 64 x 72 (padded)
    __bf16* Wl0  = SH + 4608;                       // 128 x 64 (swizzled image)
    __bf16* Wl1  = SH + 12800;
    __bf16* T    = SH + 4608;                       // V epilogue overlay, 128 x 72

    const int isV = blockIdx.x >= 256;
    const int m0  = (isV ? blockIdx.x - 256 : blockIdx.x) * 64;
    const int b   = m0 >> 11;
    const int s0  = m0 & (SS - 1);
    const int len = lengths[b];
    if (s0 >= len) return;                          // fully-padded tile

    const int tid  = threadIdx.x;
    const int wave = tid >> 6;
    const int lane = tid & 63;
    const int quad = lane >> 4;
    const int l16  = lane & 15;
    const int wm   = wave >> 1;
    const int wn   = wave & 1;

    const float*  A  = isV ? x : ctx;
    const __bf16* W0 = isV ? (Wt + 262144) : Wt;
    const __bf16* W1 = Wt + 131072;

    const int r    = tid >> 2;
    const int kseg = (tid & 3) * 16;
    const float* Ab = A + (size_t)(m0 + r) * DD + kseg;
    const int  wel  = tid * 8;                      // 16B block element offset

    floatx4 acc[2][2][4];
#pragma unroll
    for (int m_ = 0; m_ < 2; ++m_)
#pragma unroll
        for (int i = 0; i < 2; ++i)
#pragma unroll
            for (int j = 0; j < 4; ++j) acc[m_][i][j] = (floatx4){0.f,0.f,0.f,0.f};

    // register-staged A (fp32) and W (bf16 image) for the CURRENT iteration
    float4 pf[4];
    bf16x8 wr0[4], wr1[4];
#pragma unroll
    for (int i = 0; i < 4; ++i) pf[i] = *(const float4*)(Ab + i * 4);
#pragma unroll
    for (int i = 0; i < 4; ++i)
        wr0[i] = *(const bf16x8*)(W0 + i * 2048 + wel);
    if (!isV)
#pragma unroll
        for (int i = 0; i < 4; ++i)
            wr1[i] = *(const bf16x8*)(W1 + i * 2048 + wel);

    for (int t = 0; t < 16; ++t) {
        __syncthreads();                      // compute(t-1) done: LDS writable
        // ---- write staged registers (iteration t data) into LDS ----
        {
            bf16x8 c0, c1;
            c0[0]=(__bf16)pf[0].x; c0[1]=(__bf16)pf[0].y; c0[2]=(__bf16)pf[0].z; c0[3]=(__bf16)pf[0].w;
            c0[4]=(__bf16)pf[1].x; c0[5]=(__bf16)pf[1].y; c0[6]=(__bf16)pf[1].z; c0[7]=(__bf16)pf[1].w;
            c1[0]=(__bf16)pf[2].x; c1[1]=(__bf16)pf[2].y; c1[2]=(__bf16)pf[2].z; c1[3]=(__bf16)pf[2].w;
            c1[4]=(__bf16)pf[3].x; c1[5]=(__bf16)pf[3].y; c1[6]=(__bf16)pf[3].z; c1[7]=(__bf16)pf[3].w;
            *(bf16x8*)&Abuf[r * 72 + kseg]     = c0;
            *(bf16x8*)&Abuf[r * 72 + kseg + 8] = c1;
        }
#pragma unroll
        for (int i = 0; i < 4; ++i) *(bf16x8*)&Wl0[i * 2048 + wel] = wr0[i];
        if (!isV)
#pragma unroll
            for (int i = 0; i < 4; ++i) *(bf16x8*)&Wl1[i * 2048 + wel] = wr1[i];

        // ---- issue next-iteration loads (registers: stay in flight across
        //      the barrier; consumed by next iter's ds_writes) ----
        if (t < 15) {
            const float* ap = Ab + (t + 1) * 64;
#pragma unroll
            for (int i = 0; i < 4; ++i) pf[i] = *(const float4*)(ap + i * 4);
            const __bf16* wp0 = W0 + (size_t)(t + 1) * 8192 + wel;
#pragma unroll
            for (int i = 0; i < 4; ++i) wr0[i] = *(const bf16x8*)(wp0 + i * 2048);
            if (!isV) {
                const __bf16* wp1 = W1 + (size_t)(t + 1) * 8192 + wel;
#pragma unroll
                for (int i = 0; i < 4; ++i) wr1[i] = *(const bf16x8*)(wp1 + i * 2048);
            }
        }
        __syncthreads();                      // LDS writes visible

#pragma unroll
        for (int kh = 0; kh < 2; ++kh) {
            bf16x8 af[2];
#pragma unroll
            for (int mt = 0; mt < 2; ++mt)
                af[mt] = *(const bf16x8*)&Abuf[(wm*32 + mt*16 + l16) * 72 + kh*32 + quad*8];
            const int kb = kh * 4 + quad;
#pragma unroll
            for (int nt = 0; nt < 4; ++nt) {
                const int n = wn * 64 + nt * 16 + l16;
                const int off = n * 64 + ((kb ^ (n & 7)) << 3);
                bf16x8 w0 = *(const bf16x8*)&Wl0[off];
#pragma unroll
                for (int mt = 0; mt < 2; ++mt)
                    acc[0][mt][nt] = __builtin_amdgcn_mfma_f32_16x16x32_bf16(af[mt], w0, acc[0][mt][nt], 0, 0, 0);
                if (!isV) {
                    bf16x8 w1 = *(const bf16x8*)&Wl1[off];
#pragma unroll
                    for (int mt = 0; mt < 2; ++mt)
                        acc[1][mt][nt] = __builtin_amdgcn_mfma_f32_16x16x32_bf16(af[mt], w1, acc[1][mt][nt], 0, 0, 0);
                }
            }
        }
    }

    if (!isV) {
#pragma unroll
        for (int mt = 0; mt < 2; ++mt)
#pragma unroll
            for (int rr = 0; rr < 4; ++rr) {
                const int row = m0 + wm*32 + mt*16 + quad*4 + rr;
                const float mk = ((row & (SS - 1)) < len) ? 1.f : 0.f;
#pragma unroll
                for (int nt = 0; nt < 4; ++nt) {
                    const int col = wn*64 + nt*16 + l16;
                    Qb[(size_t)row * DKK + col] = (__bf16)(acc[0][mt][nt][rr] * mk);
                    Kb[(size_t)row * DKK + col] = (__bf16)(acc[1][mt][nt][rr] * mk);
                }
            }
    } else {
        __syncthreads();
#pragma unroll
        for (int mt = 0; mt < 2; ++mt)
#pragma unroll
            for (int nt = 0; nt < 4; ++nt)
#pragma unroll
                for (int rr = 0; rr < 4; ++rr) {
                    const int s = wm*32 + mt*16 + quad*4 + rr;
                    const int n = wn*64 + nt*16 + l16;
                    const float mk = (s0 + s < len) ? 1.f : 0.f;
                    T[n * 72 + s] = (__bf16)(acc[0][mt][nt][rr] * mk);
                }
        __syncthreads();
        const int n = tid >> 1, h = tid & 1;
        __bf16* dst = Vt + (size_t)b * DKK * SS + (size_t)n * SS + s0 + h * 32;
#pragma unroll
        for (int i = 0; i < 4; ++i)
            *(bf16x8*)(dst + i * 8) = *(const bf16x8*)&T[n * 72 + h * 32 + i * 8];
    }
}

// ---------------------------------------------------------------------------
// Kernel 2: per-batch column mean of V (exact output for padded q-rows).
// ---------------------------------------------------------------------------
__global__ __launch_bounds__(256) void vmean_kernel(
    const __bf16* __restrict__ Vt, const int* __restrict__ lengths,
    float* __restrict__ Vmean)
{
    const int b   = blockIdx.x >> 3;
    const int g3  = blockIdx.x & 7;
    const int len = lengths[b];
    const int tid = threadIdx.x;
    const int n   = g3 * 16 + (tid >> 4);
    const int sl  = (tid & 15) * 128;                 // this thread's 128-elem span
    const __bf16* src = Vt + (size_t)b * DKK * SS + (size_t)n * SS + sl;
    float s = 0.f;
#pragma unroll
    for (int i = 0; i < 16; ++i) {
        bf16x8 v = *(const bf16x8*)(src + i * 8);
#pragma unroll
        for (int j = 0; j < 8; ++j)
            s += (sl + i * 8 + j < len) ? (float)v[j] : 0.f;
    }
#pragma unroll
    for (int off = 1; off < 16; off <<= 1)
        s += __shfl_xor(s, off, 64);
    if ((tid & 15) == 0) Vmean[b * DKK + n] = s / (float)len;
}

// ---------------------------------------------------------------------------
// Kernel 3: flash attention.  R7 change: V is NOT LDS-staged anymore — read
// directly from global/L2 into registers inside process() (the exact PV
// pattern harness-verified in R0/R2: vf[nt] row-major from Vt, u.h x vf
// MFMA).  V was consumed exactly once, so its LDS round-trip bought nothing
// and its 32 KB halved co-residency.  LDS now 32 KB (K dbuf only) ->
// 4 blocks/CU (R6: 2), 4 independent waves/SIMD hide the per-chunk chain
// that R6's counters showed fully exposed (45 us = ~3270 cy/chunk vs
// ~1100 cy of work; occupancy 6.5%).  __launch_bounds__(256,4) caps VGPR
// at 128 so 4 blocks/CU is register-feasible.  K staging swizzle, QK frag
// layout, softmax, bpermute, 2-way reduce: verbatim R6 (verified).
// Boundary safety (V from global): every K/V row touched lies in a
// 64-aligned tile with s0 < len, which proj always writes (zeros past len).
// ---------------------------------------------------------------------------
__global__ __launch_bounds__(256, 4) void attn_kernel(
    const __bf16* __restrict__ Qb, const __bf16* __restrict__ Kb,
    const __bf16* __restrict__ Vt, const int* __restrict__ lengths,
    const float* __restrict__ Vmean, float* __restrict__ out)
{
    __shared__ __align__(16) __bf16 KB[2 * 8192];   // 2 x [64 keys][128] 32 KB

    const int b    = blockIdx.x & 7;          // batch -> XCD pin (round-robin)
    const int ii   = blockIdx.x >> 3;         // 0..63
    const int qt   = (ii < 32) ? (63 - ii) : (ii - 32);   // pair-balanced map
    const int qw   = qt * 32;
    const int len  = lengths[b];
    const int tid  = threadIdx.x;
    const int wave = tid >> 6;
    const int lane = tid & 63;
    const int quad = lane >> 4;
    const int l16  = lane & 15;
    const int sub  = wave >> 1;               // q-subtile (16 rows)
    const int half = wave & 1;                // key half (32 keys)

    if (qw >= len) {                          // fully-padded tile: exact Vmean
        const int c8 = (tid & 15) * 8;
        const float4 v0 = *(const float4*)(Vmean + b * DKK + c8);
        const float4 v1 = *(const float4*)(Vmean + b * DKK + c8 + 4);
#pragma unroll
        for (int pass = 0; pass < 2; ++pass) {
            const int row = pass * 16 + (tid >> 4);
            float* op = out + (size_t)(b * SS + qw + row) * DKK + c8;
            *(float4*)op = v0; *(float4*)(op + 4) = v1;
        }
        return;                               // whole block returns: no barrier
    }

    const int jmax = min(qw + 32, len);       // causal: keys in [0, jmax)
    const int nc   = (jmax + 63) >> 6;        // 64-key chunks
    const __bf16* Kbase = Kb + (size_t)b * SS * DKK;
    const __bf16* Vbase = Vt + (size_t)b * DKK * SS;

    // Q fragments for this wave's 16 rows
    bf16x8 qfrag[4];
    {
        const __bf16* Qbase = Qb + (size_t)(b * SS + qw + sub * 16) * DKK;
#pragma unroll
        for (int cc = 0; cc < 4; ++cc)
            qfrag[cc] = *(const bf16x8*)(Qbase + (size_t)l16 * DKK + cc * 32 + quad * 8);
    }

    floatx4 oacc[8];
#pragma unroll
    for (int nt = 0; nt < 8; ++nt) oacc[nt] = (floatx4){0.f,0.f,0.f,0.f};
    float lsum = 0.f;                         // per-lane, q = l16 (this half)
    const float scale = 0.08838834764831845f; // 1/sqrt(128)
    const int   iq    = qw + sub * 16 + l16;
    const int   sw7   = l16 & 7;              // read-side swizzle key

    auto stageK = [&](int buf, int j0) {
#pragma unroll
        for (int i = 0; i < 4; ++i) {
            const int c   = wave * 4 + i;           // 0..15
            const int row = c * 4 + quad;           // 0..63
            const int sb  = l16 ^ (row & 7);        // inverse-swizzled src blk
            lds16(Kbase + (size_t)(j0 + row) * DKK + sb * 8,
                  KB + buf * 8192 + c * 512);
        }
    };

    auto process = [&](int buf, int j0) {
        const int kbas = buf * 8192;
        // V for this wave's 32-key half, straight from global/L2 (R2-verified
        // pattern).  Issued first: latency hides under QK MFMA + softmax.
        bf16x8 vf[8];
#pragma unroll
        for (int nt = 0; nt < 8; ++nt)
            vf[nt] = *(const bf16x8*)(
                Vbase + (size_t)(nt*16 + l16) * SS + j0 + half*32 + quad*8);

        floatx4 st[2];
#pragma unroll
        for (int jt = 0; jt < 2; ++jt) {
            st[jt] = (floatx4){0.f,0.f,0.f,0.f};
#pragma unroll
            for (int cc = 0; cc < 4; ++cc) {
                bf16x8 kf = *(const bf16x8*)(
                    KB + kbas + ((half*2 + jt)*16 + l16) * 128 + (((cc*4 + quad) ^ sw7) * 8));
                st[jt] = __builtin_amdgcn_mfma_f32_16x16x32_bf16(
                    kf, qfrag[cc], st[jt], 0, 0, 0);
            }
        }
        int pk[2][2];
#pragma unroll
        for (int jt = 0; jt < 2; ++jt) {
            float p[4];
#pragma unroll
            for (int rr = 0; rr < 4; ++rr) {
                const int j = j0 + half*32 + jt*16 + quad*4 + rr;
                p[rr] = (j > iq || j >= len) ? 0.f : __expf(st[jt][rr] * scale - 8.f);
                lsum += p[rr];
            }
            pk[jt][0] = pack2(p[0], p[1]);
            pk[jt][1] = pack2(p[2], p[3]);
        }
        const int a0 = (((quad & 1) << 5) + l16) << 2;
        const int a1 = a0 + 64;
        const int r00 = __builtin_amdgcn_ds_bpermute(a0, pk[0][0]);
        const int r01 = __builtin_amdgcn_ds_bpermute(a0, pk[0][1]);
        const int r02 = __builtin_amdgcn_ds_bpermute(a0, pk[1][0]);
        const int r03 = __builtin_amdgcn_ds_bpermute(a0, pk[1][1]);
        const int r10 = __builtin_amdgcn_ds_bpermute(a1, pk[0][0]);
        const int r11 = __builtin_amdgcn_ds_bpermute(a1, pk[0][1]);
        const int r12 = __builtin_amdgcn_ds_bpermute(a1, pk[1][0]);
        const int r13 = __builtin_amdgcn_ds_bpermute(a1, pk[1][1]);
        const bool hi = quad >= 2;
        union { intx4 i; bf16x8 h; } u;
        u.i = (intx4){ hi ? r02 : r00, hi ? r03 : r01,
                       hi ? r12 : r10, hi ? r13 : r11 };
#pragma unroll
        for (int nt = 0; nt < 8; ++nt)
            oacc[nt] = __builtin_amdgcn_mfma_f32_16x16x32_bf16(
                u.h, vf[nt], oacc[nt], 0, 0, 0);
    };

    stageK(0, 0);
    __syncthreads();
    for (int c = 0; c < nc; ++c) {
        const int cur = c & 1;
        if (c + 1 < nc) stageK(cur ^ 1, (c + 1) * 64);
        process(cur, c * 64);
        __syncthreads();
    }

    lsum += __shfl_xor(lsum, 16, 64);
    lsum += __shfl_xor(lsum, 32, 64);

    // 2-way cross-wave reduce per sub-tile (overlay on KB after final barrier)
    float* Ored = (float*)KB;                 // 2 x [16][128] f32 = 16 KB
    float* Lred = (float*)KB + 4096;          // 2 x [16] f32
    if (half) {
#pragma unroll
        for (int nt = 0; nt < 8; ++nt)
#pragma unroll
            for (int rr = 0; rr < 4; ++rr)
                Ored[sub*2048 + (quad*4 + rr)*128 + nt*16 + l16] = oacc[nt][rr];
        if (lane < 16) Lred[sub*16 + l16] = lsum;
    }
    __syncthreads();
    if (!half) {
        const float lt = lsum + Lred[sub*16 + l16];   // row-total for q = l16
        float inv[4];
#pragma unroll
        for (int rr = 0; rr < 4; ++rr)
            inv[rr] = 1.f / __shfl(lt, quad * 4 + rr, 64);
#pragma unroll
        for (int nt = 0; nt < 8; ++nt)
#pragma unroll
            for (int rr = 0; rr < 4; ++rr)
                out[(size_t)(b * SS + qw + sub*16 + quad*4 + rr) * DKK + nt*16 + l16] =
                    (oacc[nt][rr] + Ored[sub*2048 + (quad*4 + rr)*128 + nt*16 + l16]) * inv[rr];
    }
}

extern "C" void kernel_launch(void* const* d_in, const int* in_sizes, int n_in,
                              void* d_out, int out_size, void* d_ws, size_t ws_size,
                              hipStream_t stream) {
    const float* x   = (const float*)d_in[0];
    const float* ctx = (const float*)d_in[1];
    const float* Wq  = (const float*)d_in[2];
    const float* Wk  = (const float*)d_in[3];
    const float* Wv  = (const float*)d_in[4];
    const int* lengths = (const int*)d_in[5];
    float* out = (float*)d_out;

    char* ws = (char*)d_ws;
    __bf16* Wt = (__bf16*)ws;                          // 768 KB
    __bf16* Qb = (__bf16*)(ws + 786432);               // 4 MB
    __bf16* Kb = (__bf16*)(ws + 786432 + 4194304);     // 4 MB
    __bf16* Vt = (__bf16*)(ws + 786432 + 8388608);     // 4 MB (V^T)
    float*  Vm = (float*) (ws + 786432 + 12582912);    // 4 KB

    convw_kernel<<<dim3(64, 3), 256, 0, stream>>>(Wq, Wk, Wv, Wt);
    proj_kernel<<<512, 256, 0, stream>>>(x, ctx, Wt, lengths, Qb, Kb, Vt);
    vmean_kernel<<<64, 256, 0, stream>>>(Vt, lengths, Vm);
    attn_kernel<<<512, 256, 0, stream>>>(Qb, Kb, Vt, lengths, Vm, out);
}

// Round 9
// 210.766 us; speedup vs baseline: 1.0884x; 1.0884x over previous
//
#include <hip/hip_runtime.h>
#include <hip/hip_bf16.h>

// Problem dims (fixed by setup_inputs)
#define BB 8
#define SS 2048
#define DD 1024
#define DKK 128

using bf16x8  = __attribute__((ext_vector_type(8))) __bf16;
using floatx4 = __attribute__((ext_vector_type(4))) float;
using intx4   = __attribute__((ext_vector_type(4))) int;

// async global->LDS, 16B/lane. LDS dest = wave-uniform base + lane*16 (HW rule).
__device__ __forceinline__ void lds16(const void* g, void* l) {
    __builtin_amdgcn_global_load_lds((const __attribute__((address_space(1))) void*)g,
                                     (__attribute__((address_space(3))) void*)l, 16, 0, 0);
}

__device__ __forceinline__ int pack2(float a, float b) {
    union { __bf16 h; unsigned short u; } ua, ub;
    ua.h = (__bf16)a; ub.h = (__bf16)b;
    return (int)(ua.u | ((unsigned)ub.u << 16));
}

// ---------------------------------------------------------------------------
// Kernel 0: W (fp32 [128][1024]) -> bf16, k-tile-major + 16B-block XOR swizzle
// ---------------------------------------------------------------------------
__global__ __launch_bounds__(256) void convw_kernel(
    const float* __restrict__ Wq, const float* __restrict__ Wk,
    const float* __restrict__ Wv, __bf16* __restrict__ Wt)
{
    const int z = blockIdx.y;
    const float* W = (z == 0) ? Wq : (z == 1) ? Wk : Wv;
    const int t  = blockIdx.x * 256 + threadIdx.x;   // 0..16383
    const int n  = t >> 7;
    const int k0 = (t & 127) * 8;
    float4 f0 = *(const float4*)(W + n * DD + k0);
    float4 f1 = *(const float4*)(W + n * DD + k0 + 4);
    bf16x8 v;
    v[0]=(__bf16)f0.x; v[1]=(__bf16)f0.y; v[2]=(__bf16)f0.z; v[3]=(__bf16)f0.w;
    v[4]=(__bf16)f1.x; v[5]=(__bf16)f1.y; v[6]=(__bf16)f1.z; v[7]=(__bf16)f1.w;
    const int kb  = (k0 >> 3) & 7;
    const int kbs = kb ^ (n & 7);
    *(bf16x8*)(Wt + (size_t)z * 131072 + ((k0 >> 6) * 128 + n) * 64 + kbs * 8) = v;
}

// ---------------------------------------------------------------------------
// Kernel 1: projections (unchanged from R6 — conflict-free W reg-staging).
// ---------------------------------------------------------------------------
__global__ __launch_bounds__(256) void proj_kernel(
    const float* __restrict__ x, const float* __restrict__ ctx,
    const __bf16* __restrict__ Wt, const int* __restrict__ lengths,
    __bf16* __restrict__ Qb, __bf16* __restrict__ Kb, __bf16* __restrict__ Vt)
{
    __shared__ __align__(16) __bf16 SH[20992];      // 41984 B
    __bf16* Abuf = SH;                              // 64 x 72 (padded)
    __bf16* Wl0  = SH + 4608;                       // 128 x 64 (swizzled image)
    __bf16* Wl1  = SH + 12800;
    __bf16* T    = SH + 4608;                       // V epilogue overlay, 128 x 72

    const int isV = blockIdx.x >= 256;
    const int m0  = (isV ? blockIdx.x - 256 : blockIdx.x) * 64;
    const int b   = m0 >> 11;
    const int s0  = m0 & (SS - 1);
    const int len = lengths[b];
    if (s0 >= len) return;                          // fully-padded tile

    const int tid  = threadIdx.x;
    const int wave = tid >> 6;
    const int lane = tid & 63;
    const int quad = lane >> 4;
    const int l16  = lane & 15;
    const int wm   = wave >> 1;
    const int wn   = wave & 1;

    const float*  A  = isV ? x : ctx;
    const __bf16* W0 = isV ? (Wt + 262144) : Wt;
    const __bf16* W1 = Wt + 131072;

    const int r    = tid >> 2;
    const int kseg = (tid & 3) * 16;
    const float* Ab = A + (size_t)(m0 + r) * DD + kseg;
    const int  wel  = tid * 8;                      // 16B block element offset

    floatx4 acc[2][2][4];
#pragma unroll
    for (int m_ = 0; m_ < 2; ++m_)
#pragma unroll
        for (int i = 0; i < 2; ++i)
#pragma unroll
            for (int j = 0; j < 4; ++j) acc[m_][i][j] = (floatx4){0.f,0.f,0.f,0.f};

    // register-staged A (fp32) and W (bf16 image) for the CURRENT iteration
    float4 pf[4];
    bf16x8 wr0[4], wr1[4];
#pragma unroll
    for (int i = 0; i < 4; ++i) pf[i] = *(const float4*)(Ab + i * 4);
#pragma unroll
    for (int i = 0; i < 4; ++i)
        wr0[i] = *(const bf16x8*)(W0 + i * 2048 + wel);
    if (!isV)
#pragma unroll
        for (int i = 0; i < 4; ++i)
            wr1[i] = *(const bf16x8*)(W1 + i * 2048 + wel);

    for (int t = 0; t < 16; ++t) {
        __syncthreads();                      // compute(t-1) done: LDS writable
        // ---- write staged registers (iteration t data) into LDS ----
        {
            bf16x8 c0, c1;
            c0[0]=(__bf16)pf[0].x; c0[1]=(__bf16)pf[0].y; c0[2]=(__bf16)pf[0].z; c0[3]=(__bf16)pf[0].w;
            c0[4]=(__bf16)pf[1].x; c0[5]=(__bf16)pf[1].y; c0[6]=(__bf16)pf[1].z; c0[7]=(__bf16)pf[1].w;
            c1[0]=(__bf16)pf[2].x; c1[1]=(__bf16)pf[2].y; c1[2]=(__bf16)pf[2].z; c1[3]=(__bf16)pf[2].w;
            c1[4]=(__bf16)pf[3].x; c1[5]=(__bf16)pf[3].y; c1[6]=(__bf16)pf[3].z; c1[7]=(__bf16)pf[3].w;
            *(bf16x8*)&Abuf[r * 72 + kseg]     = c0;
            *(bf16x8*)&Abuf[r * 72 + kseg + 8] = c1;
        }
#pragma unroll
        for (int i = 0; i < 4; ++i) *(bf16x8*)&Wl0[i * 2048 + wel] = wr0[i];
        if (!isV)
#pragma unroll
            for (int i = 0; i < 4; ++i) *(bf16x8*)&Wl1[i * 2048 + wel] = wr1[i];

        // ---- issue next-iteration loads (registers: stay in flight across
        //      the barrier; consumed by next iter's ds_writes) ----
        if (t < 15) {
            const float* ap = Ab + (t + 1) * 64;
#pragma unroll
            for (int i = 0; i < 4; ++i) pf[i] = *(const float4*)(ap + i * 4);
            const __bf16* wp0 = W0 + (size_t)(t + 1) * 8192 + wel;
#pragma unroll
            for (int i = 0; i < 4; ++i) wr0[i] = *(const bf16x8*)(wp0 + i * 2048);
            if (!isV) {
                const __bf16* wp1 = W1 + (size_t)(t + 1) * 8192 + wel;
#pragma unroll
                for (int i = 0; i < 4; ++i) wr1[i] = *(const bf16x8*)(wp1 + i * 2048);
            }
        }
        __syncthreads();                      // LDS writes visible

#pragma unroll
        for (int kh = 0; kh < 2; ++kh) {
            bf16x8 af[2];
#pragma unroll
            for (int mt = 0; mt < 2; ++mt)
                af[mt] = *(const bf16x8*)&Abuf[(wm*32 + mt*16 + l16) * 72 + kh*32 + quad*8];
            const int kb = kh * 4 + quad;
#pragma unroll
            for (int nt = 0; nt < 4; ++nt) {
                const int n = wn * 64 + nt * 16 + l16;
                const int off = n * 64 + ((kb ^ (n & 7)) << 3);
                bf16x8 w0 = *(const bf16x8*)&Wl0[off];
#pragma unroll
                for (int mt = 0; mt < 2; ++mt)
                    acc[0][mt][nt] = __builtin_amdgcn_mfma_f32_16x16x32_bf16(af[mt], w0, acc[0][mt][nt], 0, 0, 0);
                if (!isV) {
                    bf16x8 w1 = *(const bf16x8*)&Wl1[off];
#pragma unroll
                    for (int mt = 0; mt < 2; ++mt)
                        acc[1][mt][nt] = __builtin_amdgcn_mfma_f32_16x16x32_bf16(af[mt], w1, acc[1][mt][nt], 0, 0, 0);
                }
            }
        }
    }

    if (!isV) {
#pragma unroll
        for (int mt = 0; mt < 2; ++mt)
#pragma unroll
            for (int rr = 0; rr < 4; ++rr) {
                const int row = m0 + wm*32 + mt*16 + quad*4 + rr;
                const float mk = ((row & (SS - 1)) < len) ? 1.f : 0.f;
#pragma unroll
                for (int nt = 0; nt < 4; ++nt) {
                    const int col = wn*64 + nt*16 + l16;
                    Qb[(size_t)row * DKK + col] = (__bf16)(acc[0][mt][nt][rr] * mk);
                    Kb[(size_t)row * DKK + col] = (__bf16)(acc[1][mt][nt][rr] * mk);
                }
            }
    } else {
        __syncthreads();
#pragma unroll
        for (int mt = 0; mt < 2; ++mt)
#pragma unroll
            for (int nt = 0; nt < 4; ++nt)
#pragma unroll
                for (int rr = 0; rr < 4; ++rr) {
                    const int s = wm*32 + mt*16 + quad*4 + rr;
                    const int n = wn*64 + nt*16 + l16;
                    const float mk = (s0 + s < len) ? 1.f : 0.f;
                    T[n * 72 + s] = (__bf16)(acc[0][mt][nt][rr] * mk);
                }
        __syncthreads();
        const int n = tid >> 1, h = tid & 1;
        __bf16* dst = Vt + (size_t)b * DKK * SS + (size_t)n * SS + s0 + h * 32;
#pragma unroll
        for (int i = 0; i < 4; ++i)
            *(bf16x8*)(dst + i * 8) = *(const bf16x8*)&T[n * 72 + h * 32 + i * 8];
    }
}

// ---------------------------------------------------------------------------
// Kernel 2: per-batch column mean of V (exact output for padded q-rows).
// ---------------------------------------------------------------------------
__global__ __launch_bounds__(256) void vmean_kernel(
    const __bf16* __restrict__ Vt, const int* __restrict__ lengths,
    float* __restrict__ Vmean)
{
    const int b   = blockIdx.x >> 3;
    const int g3  = blockIdx.x & 7;
    const int len = lengths[b];
    const int tid = threadIdx.x;
    const int n   = g3 * 16 + (tid >> 4);
    const int sl  = (tid & 15) * 128;                 // this thread's 128-elem span
    const __bf16* src = Vt + (size_t)b * DKK * SS + (size_t)n * SS + sl;
    float s = 0.f;
#pragma unroll
    for (int i = 0; i < 16; ++i) {
        bf16x8 v = *(const bf16x8*)(src + i * 8);
#pragma unroll
        for (int j = 0; j < 8; ++j)
            s += (sl + i * 8 + j < len) ? (float)v[j] : 0.f;
    }
#pragma unroll
    for (int off = 1; off < 16; off <<= 1)
        s += __shfl_xor(s, off, 64);
    if ((tid & 15) == 0) Vmean[b * DKK + n] = s / (float)len;
}

// ---------------------------------------------------------------------------
// Kernel 3: flash attention.  R8 change: ONLY the launch bounds.
// R7's __launch_bounds__(256,4) told the allocator "4 waves/EU" -> clamped
// VGPR to 64, far below the live set (vf[8]=32 + oacc=32 + qfrag=16 + temps)
// -> V loads serialized/spilled, V latency fully exposed -> 45->65 us
// regression.  Plain __launch_bounds__(256) lets the allocator keep the
// working set (~104-120 VGPR expected, as R2's similar code used 120);
// at <=128 VGPR we still get 4 waves/SIMD and (LDS 32 KB) 4 blocks/CU,
// with vf[8] genuinely in flight under QK+softmax.
// Structure (verified R7 pass): K-only LDS dbuf (32 KB, swizzled
// global_load_lds); V straight from global/L2 (R0/R2-verified PV pattern);
// fixed-max softmax; bpermute C->A; 2-way cross-wave reduce; qt pair map.
// ---------------------------------------------------------------------------
__global__ __launch_bounds__(256) void attn_kernel(
    const __bf16* __restrict__ Qb, const __bf16* __restrict__ Kb,
    const __bf16* __restrict__ Vt, const int* __restrict__ lengths,
    const float* __restrict__ Vmean, float* __restrict__ out)
{
    __shared__ __align__(16) __bf16 KB[2 * 8192];   // 2 x [64 keys][128] 32 KB

    const int b    = blockIdx.x & 7;          // batch -> XCD pin (round-robin)
    const int ii   = blockIdx.x >> 3;         // 0..63
    const int qt   = (ii < 32) ? (63 - ii) : (ii - 32);   // pair-balanced map
    const int qw   = qt * 32;
    const int len  = lengths[b];
    const int tid  = threadIdx.x;
    const int wave = tid >> 6;
    const int lane = tid & 63;
    const int quad = lane >> 4;
    const int l16  = lane & 15;
    const int sub  = wave >> 1;               // q-subtile (16 rows)
    const int half = wave & 1;                // key half (32 keys)

    if (qw >= len) {                          // fully-padded tile: exact Vmean
        const int c8 = (tid & 15) * 8;
        const float4 v0 = *(const float4*)(Vmean + b * DKK + c8);
        const float4 v1 = *(const float4*)(Vmean + b * DKK + c8 + 4);
#pragma unroll
        for (int pass = 0; pass < 2; ++pass) {
            const int row = pass * 16 + (tid >> 4);
            float* op = out + (size_t)(b * SS + qw + row) * DKK + c8;
            *(float4*)op = v0; *(float4*)(op + 4) = v1;
        }
        return;                               // whole block returns: no barrier
    }

    const int jmax = min(qw + 32, len);       // causal: keys in [0, jmax)
    const int nc   = (jmax + 63) >> 6;        // 64-key chunks
    const __bf16* Kbase = Kb + (size_t)b * SS * DKK;
    const __bf16* Vbase = Vt + (size_t)b * DKK * SS;

    // Q fragments for this wave's 16 rows
    bf16x8 qfrag[4];
    {
        const __bf16* Qbase = Qb + (size_t)(b * SS + qw + sub * 16) * DKK;
#pragma unroll
        for (int cc = 0; cc < 4; ++cc)
            qfrag[cc] = *(const bf16x8*)(Qbase + (size_t)l16 * DKK + cc * 32 + quad * 8);
    }

    floatx4 oacc[8];
#pragma unroll
    for (int nt = 0; nt < 8; ++nt) oacc[nt] = (floatx4){0.f,0.f,0.f,0.f};
    float lsum = 0.f;                         // per-lane, q = l16 (this half)
    const float scale = 0.08838834764831845f; // 1/sqrt(128)
    const int   iq    = qw + sub * 16 + l16;
    const int   sw7   = l16 & 7;              // read-side swizzle key

    auto stageK = [&](int buf, int j0) {
#pragma unroll
        for (int i = 0; i < 4; ++i) {
            const int c   = wave * 4 + i;           // 0..15
            const int row = c * 4 + quad;           // 0..63
            const int sb  = l16 ^ (row & 7);        // inverse-swizzled src blk
            lds16(Kbase + (size_t)(j0 + row) * DKK + sb * 8,
                  KB + buf * 8192 + c * 512);
        }
    };

    auto process = [&](int buf, int j0) {
        const int kbas = buf * 8192;
        // V for this wave's 32-key half, straight from global/L2 (R2-verified
        // pattern).  Issued first: latency hides under QK MFMA + softmax.
        bf16x8 vf[8];
#pragma unroll
        for (int nt = 0; nt < 8; ++nt)
            vf[nt] = *(const bf16x8*)(
                Vbase + (size_t)(nt*16 + l16) * SS + j0 + half*32 + quad*8);

        floatx4 st[2];
#pragma unroll
        for (int jt = 0; jt < 2; ++jt) {
            st[jt] = (floatx4){0.f,0.f,0.f,0.f};
#pragma unroll
            for (int cc = 0; cc < 4; ++cc) {
                bf16x8 kf = *(const bf16x8*)(
                    KB + kbas + ((half*2 + jt)*16 + l16) * 128 + (((cc*4 + quad) ^ sw7) * 8));
                st[jt] = __builtin_amdgcn_mfma_f32_16x16x32_bf16(
                    kf, qfrag[cc], st[jt], 0, 0, 0);
            }
        }
        int pk[2][2];
#pragma unroll
        for (int jt = 0; jt < 2; ++jt) {
            float p[4];
#pragma unroll
            for (int rr = 0; rr < 4; ++rr) {
                const int j = j0 + half*32 + jt*16 + quad*4 + rr;
                p[rr] = (j > iq || j >= len) ? 0.f : __expf(st[jt][rr] * scale - 8.f);
                lsum += p[rr];
            }
            pk[jt][0] = pack2(p[0], p[1]);
            pk[jt][1] = pack2(p[2], p[3]);
        }
        const int a0 = (((quad & 1) << 5) + l16) << 2;
        const int a1 = a0 + 64;
        const int r00 = __builtin_amdgcn_ds_bpermute(a0, pk[0][0]);
        const int r01 = __builtin_amdgcn_ds_bpermute(a0, pk[0][1]);
        const int r02 = __builtin_amdgcn_ds_bpermute(a0, pk[1][0]);
        const int r03 = __builtin_amdgcn_ds_bpermute(a0, pk[1][1]);
        const int r10 = __builtin_amdgcn_ds_bpermute(a1, pk[0][0]);
        const int r11 = __builtin_amdgcn_ds_bpermute(a1, pk[0][1]);
        const int r12 = __builtin_amdgcn_ds_bpermute(a1, pk[1][0]);
        const int r13 = __builtin_amdgcn_ds_bpermute(a1, pk[1][1]);
        const bool hi = quad >= 2;
        union { intx4 i; bf16x8 h; } u;
        u.i = (intx4){ hi ? r02 : r00, hi ? r03 : r01,
                       hi ? r12 : r10, hi ? r13 : r11 };
#pragma unroll
        for (int nt = 0; nt < 8; ++nt)
            oacc[nt] = __builtin_amdgcn_mfma_f32_16x16x32_bf16(
                u.h, vf[nt], oacc[nt], 0, 0, 0);
    };

    stageK(0, 0);
    __syncthreads();
    for (int c = 0; c < nc; ++c) {
        const int cur = c & 1;
        if (c + 1 < nc) stageK(cur ^ 1, (c + 1) * 64);
        process(cur, c * 64);
        __syncthreads();
    }

    lsum += __shfl_xor(lsum, 16, 64);
    lsum += __shfl_xor(lsum, 32, 64);

    // 2-way cross-wave reduce per sub-tile (overlay on KB after final barrier)
    float* Ored = (float*)KB;                 // 2 x [16][128] f32 = 16 KB
    float* Lred = (float*)KB + 4096;          // 2 x [16] f32
    if (half) {
#pragma unroll
        for (int nt = 0; nt < 8; ++nt)
#pragma unroll
            for (int rr = 0; rr < 4; ++rr)
                Ored[sub*2048 + (quad*4 + rr)*128 + nt*16 + l16] = oacc[nt][rr];
        if (lane < 16) Lred[sub*16 + l16] = lsum;
    }
    __syncthreads();
    if (!half) {
        const float lt = lsum + Lred[sub*16 + l16];   // row-total for q = l16
        float inv[4];
#pragma unroll
        for (int rr = 0; rr < 4; ++rr)
            inv[rr] = 1.f / __shfl(lt, quad * 4 + rr, 64);
#pragma unroll
        for (int nt = 0; nt < 8; ++nt)
#pragma unroll
            for (int rr = 0; rr < 4; ++rr)
                out[(size_t)(b * SS + qw + sub*16 + quad*4 + rr) * DKK + nt*16 + l16] =
                    (oacc[nt][rr] + Ored[sub*2048 + (quad*4 + rr)*128 + nt*16 + l16]) * inv[rr];
    }
}

extern "C" void kernel_launch(void* const* d_in, const int* in_sizes, int n_in,
                              void* d_out, int out_size, void* d_ws, size_t ws_size,
                              hipStream_t stream) {
    const float* x   = (const float*)d_in[0];
    const float* ctx = (const float*)d_in[1];
    const float* Wq  = (const float*)d_in[2];
    const float* Wk  = (const float*)d_in[3];
    const float* Wv  = (const float*)d_in[4];
    const int* lengths = (const int*)d_in[5];
    float* out = (float*)d_out;

    char* ws = (char*)d_ws;
    __bf16* Wt = (__bf16*)ws;                          // 768 KB
    __bf16* Qb = (__bf16*)(ws + 786432);               // 4 MB
    __bf16* Kb = (__bf16*)(ws + 786432 + 4194304);     // 4 MB
    __bf16* Vt = (__bf16*)(ws + 786432 + 8388608);     // 4 MB (V^T)
    float*  Vm = (float*) (ws + 786432 + 12582912);    // 4 KB

    convw_kernel<<<dim3(64, 3), 256, 0, stream>>>(Wq, Wk, Wv, Wt);
    proj_kernel<<<512, 256, 0, stream>>>(x, ctx, Wt, lengths, Qb, Kb, Vt);
    vmean_kernel<<<64, 256, 0, stream>>>(Vt, lengths, Vm);
    attn_kernel<<<512, 256, 0, stream>>>(Qb, Kb, Vt, lengths, Vm, out);
}

// Round 11
// 208.061 us; speedup vs baseline: 1.1026x; 1.0130x over previous
//
#include <hip/hip_runtime.h>
#include <hip/hip_bf16.h>

// Problem dims (fixed by setup_inputs)
#define BB 8
#define SS 2048
#define DD 1024
#define DKK 128

using bf16x8  = __attribute__((ext_vector_type(8))) __bf16;
using floatx4 = __attribute__((ext_vector_type(4))) float;
using intx4   = __attribute__((ext_vector_type(4))) int;

// async global->LDS, 16B/lane. LDS dest = wave-uniform base + lane*16 (HW rule).
__device__ __forceinline__ void lds16(const void* g, void* l) {
    __builtin_amdgcn_global_load_lds((const __attribute__((address_space(1))) void*)g,
                                     (__attribute__((address_space(3))) void*)l, 16, 0, 0);
}

__device__ __forceinline__ int pack2(float a, float b) {
    union { __bf16 h; unsigned short u; } ua, ub;
    ua.h = (__bf16)a; ub.h = (__bf16)b;
    return (int)(ua.u | ((unsigned)ub.u << 16));
}

// ---------------------------------------------------------------------------
// Kernel 0: W (fp32 [128][1024]) -> bf16, k-tile-major + 16B-block XOR swizzle
// ---------------------------------------------------------------------------
__global__ __launch_bounds__(256) void convw_kernel(
    const float* __restrict__ Wq, const float* __restrict__ Wk,
    const float* __restrict__ Wv, __bf16* __restrict__ Wt)
{
    const int z = blockIdx.y;
    const float* W = (z == 0) ? Wq : (z == 1) ? Wk : Wv;
    const int t  = blockIdx.x * 256 + threadIdx.x;   // 0..16383
    const int n  = t >> 7;
    const int k0 = (t & 127) * 8;
    float4 f0 = *(const float4*)(W + n * DD + k0);
    float4 f1 = *(const float4*)(W + n * DD + k0 + 4);
    bf16x8 v;
    v[0]=(__bf16)f0.x; v[1]=(__bf16)f0.y; v[2]=(__bf16)f0.z; v[3]=(__bf16)f0.w;
    v[4]=(__bf16)f1.x; v[5]=(__bf16)f1.y; v[6]=(__bf16)f1.z; v[7]=(__bf16)f1.w;
    const int kb  = (k0 >> 3) & 7;
    const int kbs = kb ^ (n & 7);
    *(bf16x8*)(Wt + (size_t)z * 131072 + ((k0 >> 6) * 128 + n) * 64 + kbs * 8) = v;
}

// ---------------------------------------------------------------------------
// Kernel 1: projections (unchanged from R6 — conflict-free W reg-staging).
// ---------------------------------------------------------------------------
__global__ __launch_bounds__(256) void proj_kernel(
    const float* __restrict__ x, const float* __restrict__ ctx,
    const __bf16* __restrict__ Wt, const int* __restrict__ lengths,
    __bf16* __restrict__ Qb, __bf16* __restrict__ Kb, __bf16* __restrict__ Vt)
{
    __shared__ __align__(16) __bf16 SH[20992];      // 41984 B
    __bf16* Abuf = SH;                              // 64 x 72 (padded)
    __bf16* Wl0  = SH + 4608;                       // 128 x 64 (swizzled image)
    __bf16* Wl1  = SH + 12800;
    __bf16* T    = SH + 4608;                       // V epilogue overlay, 128 x 72

    const int isV = blockIdx.x >= 256;
    const int m0  = (isV ? blockIdx.x - 256 : blockIdx.x) * 64;
    const int b   = m0 >> 11;
    const int s0  = m0 & (SS - 1);
    const int len = lengths[b];
    if (s0 >= len) return;                          // fully-padded tile

    const int tid  = threadIdx.x;
    const int wave = tid >> 6;
    const int lane = tid & 63;
    const int quad = lane >> 4;
    const int l16  = lane & 15;
    const int wm   = wave >> 1;
    const int wn   = wave & 1;

    const float*  A  = isV ? x : ctx;
    const __bf16* W0 = isV ? (Wt + 262144) : Wt;
    const __bf16* W1 = Wt + 131072;

    const int r    = tid >> 2;
    const int kseg = (tid & 3) * 16;
    const float* Ab = A + (size_t)(m0 + r) * DD + kseg;
    const int  wel  = tid * 8;                      // 16B block element offset

    floatx4 acc[2][2][4];
#pragma unroll
    for (int m_ = 0; m_ < 2; ++m_)
#pragma unroll
        for (int i = 0; i < 2; ++i)
#pragma unroll
            for (int j = 0; j < 4; ++j) acc[m_][i][j] = (floatx4){0.f,0.f,0.f,0.f};

    // register-staged A (fp32) and W (bf16 image) for the CURRENT iteration
    float4 pf[4];
    bf16x8 wr0[4], wr1[4];
#pragma unroll
    for (int i = 0; i < 4; ++i) pf[i] = *(const float4*)(Ab + i * 4);
#pragma unroll
    for (int i = 0; i < 4; ++i)
        wr0[i] = *(const bf16x8*)(W0 + i * 2048 + wel);
    if (!isV)
#pragma unroll
        for (int i = 0; i < 4; ++i)
            wr1[i] = *(const bf16x8*)(W1 + i * 2048 + wel);

    for (int t = 0; t < 16; ++t) {
        __syncthreads();                      // compute(t-1) done: LDS writable
        // ---- write staged registers (iteration t data) into LDS ----
        {
            bf16x8 c0, c1;
            c0[0]=(__bf16)pf[0].x; c0[1]=(__bf16)pf[0].y; c0[2]=(__bf16)pf[0].z; c0[3]=(__bf16)pf[0].w;
            c0[4]=(__bf16)pf[1].x; c0[5]=(__bf16)pf[1].y; c0[6]=(__bf16)pf[1].z; c0[7]=(__bf16)pf[1].w;
            c1[0]=(__bf16)pf[2].x; c1[1]=(__bf16)pf[2].y; c1[2]=(__bf16)pf[2].z; c1[3]=(__bf16)pf[2].w;
            c1[4]=(__bf16)pf[3].x; c1[5]=(__bf16)pf[3].y; c1[6]=(__bf16)pf[3].z; c1[7]=(__bf16)pf[3].w;
            *(bf16x8*)&Abuf[r * 72 + kseg]     = c0;
            *(bf16x8*)&Abuf[r * 72 + kseg + 8] = c1;
        }
#pragma unroll
        for (int i = 0; i < 4; ++i) *(bf16x8*)&Wl0[i * 2048 + wel] = wr0[i];
        if (!isV)
#pragma unroll
            for (int i = 0; i < 4; ++i) *(bf16x8*)&Wl1[i * 2048 + wel] = wr1[i];

        // ---- issue next-iteration loads (registers: stay in flight across
        //      the barrier; consumed by next iter's ds_writes) ----
        if (t < 15) {
            const float* ap = Ab + (t + 1) * 64;
#pragma unroll
            for (int i = 0; i < 4; ++i) pf[i] = *(const float4*)(ap + i * 4);
            const __bf16* wp0 = W0 + (size_t)(t + 1) * 8192 + wel;
#pragma unroll
            for (int i = 0; i < 4; ++i) wr0[i] = *(const bf16x8*)(wp0 + i * 2048);
            if (!isV) {
                const __bf16* wp1 = W1 + (size_t)(t + 1) * 8192 + wel;
#pragma unroll
                for (int i = 0; i < 4; ++i) wr1[i] = *(const bf16x8*)(wp1 + i * 2048);
            }
        }
        __syncthreads();                      // LDS writes visible

#pragma unroll
        for (int kh = 0; kh < 2; ++kh) {
            bf16x8 af[2];
#pragma unroll
            for (int mt = 0; mt < 2; ++mt)
                af[mt] = *(const bf16x8*)&Abuf[(wm*32 + mt*16 + l16) * 72 + kh*32 + quad*8];
            const int kb = kh * 4 + quad;
#pragma unroll
            for (int nt = 0; nt < 4; ++nt) {
                const int n = wn * 64 + nt * 16 + l16;
                const int off = n * 64 + ((kb ^ (n & 7)) << 3);
                bf16x8 w0 = *(const bf16x8*)&Wl0[off];
#pragma unroll
                for (int mt = 0; mt < 2; ++mt)
                    acc[0][mt][nt] = __builtin_amdgcn_mfma_f32_16x16x32_bf16(af[mt], w0, acc[0][mt][nt], 0, 0, 0);
                if (!isV) {
                    bf16x8 w1 = *(const bf16x8*)&Wl1[off];
#pragma unroll
                    for (int mt = 0; mt < 2; ++mt)
                        acc[1][mt][nt] = __builtin_amdgcn_mfma_f32_16x16x32_bf16(af[mt], w1, acc[1][mt][nt], 0, 0, 0);
                }
            }
        }
    }

    if (!isV) {
#pragma unroll
        for (int mt = 0; mt < 2; ++mt)
#pragma unroll
            for (int rr = 0; rr < 4; ++rr) {
                const int row = m0 + wm*32 + mt*16 + quad*4 + rr;
                const float mk = ((row & (SS - 1)) < len) ? 1.f : 0.f;
#pragma unroll
                for (int nt = 0; nt < 4; ++nt) {
                    const int col = wn*64 + nt*16 + l16;
                    Qb[(size_t)row * DKK + col] = (__bf16)(acc[0][mt][nt][rr] * mk);
                    Kb[(size_t)row * DKK + col] = (__bf16)(acc[1][mt][nt][rr] * mk);
                }
            }
    } else {
        __syncthreads();
#pragma unroll
        for (int mt = 0; mt < 2; ++mt)
#pragma unroll
            for (int nt = 0; nt < 4; ++nt)
#pragma unroll
                for (int rr = 0; rr < 4; ++rr) {
                    const int s = wm*32 + mt*16 + quad*4 + rr;
                    const int n = wn*64 + nt*16 + l16;
                    const float mk = (s0 + s < len) ? 1.f : 0.f;
                    T[n * 72 + s] = (__bf16)(acc[0][mt][nt][rr] * mk);
                }
        __syncthreads();
        const int n = tid >> 1, h = tid & 1;
        __bf16* dst = Vt + (size_t)b * DKK * SS + (size_t)n * SS + s0 + h * 32;
#pragma unroll
        for (int i = 0; i < 4; ++i)
            *(bf16x8*)(dst + i * 8) = *(const bf16x8*)&T[n * 72 + h * 32 + i * 8];
    }
}

// ---------------------------------------------------------------------------
// Kernel 2: per-batch column mean of V (exact output for padded q-rows).
// ---------------------------------------------------------------------------
__global__ __launch_bounds__(256) void vmean_kernel(
    const __bf16* __restrict__ Vt, const int* __restrict__ lengths,
    float* __restrict__ Vmean)
{
    const int b   = blockIdx.x >> 3;
    const int g3  = blockIdx.x & 7;
    const int len = lengths[b];
    const int tid = threadIdx.x;
    const int n   = g3 * 16 + (tid >> 4);
    const int sl  = (tid & 15) * 128;                 // this thread's 128-elem span
    const __bf16* src = Vt + (size_t)b * DKK * SS + (size_t)n * SS + sl;
    float s = 0.f;
#pragma unroll
    for (int i = 0; i < 16; ++i) {
        bf16x8 v = *(const bf16x8*)(src + i * 8);
#pragma unroll
        for (int j = 0; j < 8; ++j)
            s += (sl + i * 8 + j < len) ? (float)v[j] : 0.f;
    }
#pragma unroll
    for (int off = 1; off < 16; off <<= 1)
        s += __shfl_xor(s, off, 64);
    if ((tid & 15) == 0) Vmean[b * DKK + n] = s / (float)len;
}

// ---------------------------------------------------------------------------
// Kernel 3: flash attention.  R9 insight: occupancy 7.5% ~= 2.4 waves/CU —
// the R6 pair map balanced per-CU TOTALS but not CONCURRENCY (short partner
// finishes instantly; long block runs alone, chain exposed).  New shape:
//   - block = ONE 16-row q-tile, grid 1024 (8 b x 128 t), longest-first ->
//     LPT with dynamic refill sustains 2 blocks/CU x 4 waves = 2 waves/SIMD
//     for the whole kernel (LDS 64 KB = exactly 2 blocks/CU).
//   - chunk = 128 keys, K dbuf in LDS (2x32 KB, same XOR swizzle); the 4
//     waves each take a 32-key slice (h = wave) -> per-wave inner code is
//     VERBATIM R9 (QK frags, mask, pack, bpermute, PV); barriers per key
//     halve vs the 64-key chunk.
//   - V from global (R9-verified pattern) with jv>=len guard (avoids 0*NaN
//     from unwritten rows on fully-masked slices).  K reads past len are
//     NaN-safe: p is masked by j>=len before exp, independent of st.
//   - end: 4-way LDS reduce (waves 1-3 write 24KB partials into KB overlay,
//     wave 0 combines + writes out).  No atomics.
// ---------------------------------------------------------------------------
__global__ __launch_bounds__(256) void attn_kernel(
    const __bf16* __restrict__ Qb, const __bf16* __restrict__ Kb,
    const __bf16* __restrict__ Vt, const int* __restrict__ lengths,
    const float* __restrict__ Vmean, float* __restrict__ out)
{
    __shared__ __align__(16) __bf16 KB[2 * 16384];  // 2 x [128 keys][128] 64 KB

    const int b    = blockIdx.x & 7;          // batch -> XCD pin (round-robin)
    const int t    = 127 - (blockIdx.x >> 3); // longest tiles first (LPT)
    const int qw   = t * 16;
    const int len  = lengths[b];
    const int tid  = threadIdx.x;
    const int wave = tid >> 6;                // = key-slice h (0..3)
    const int lane = tid & 63;
    const int quad = lane >> 4;
    const int l16  = lane & 15;

    if (qw >= len) {                          // fully-padded tile: exact Vmean
        const int row = tid >> 4;
        const int c8  = (tid & 15) * 8;
        const float4 v0 = *(const float4*)(Vmean + b * DKK + c8);
        const float4 v1 = *(const float4*)(Vmean + b * DKK + c8 + 4);
        float* op = out + (size_t)(b * SS + qw + row) * DKK + c8;
        *(float4*)op = v0; *(float4*)(op + 4) = v1;
        return;                               // whole block returns: no barrier
    }

    const int jmax = min(qw + 16, len);       // causal: keys in [0, jmax)
    const int nc   = (jmax + 127) >> 7;       // 128-key chunks
    const __bf16* Kbase = Kb + (size_t)b * SS * DKK;
    const __bf16* Vbase = Vt + (size_t)b * DKK * SS;

    // Q fragments for the tile's 16 rows (shared by all 4 waves)
    bf16x8 qfrag[4];
    {
        const __bf16* Qbase = Qb + (size_t)(b * SS + qw) * DKK;
#pragma unroll
        for (int cc = 0; cc < 4; ++cc)
            qfrag[cc] = *(const bf16x8*)(Qbase + (size_t)l16 * DKK + cc * 32 + quad * 8);
    }

    floatx4 oacc[8];
#pragma unroll
    for (int nt = 0; nt < 8; ++nt) oacc[nt] = (floatx4){0.f,0.f,0.f,0.f};
    float lsum = 0.f;                         // per-lane, q = l16 (this slice)
    const float scale = 0.08838834764831845f; // 1/sqrt(128)
    const int   iq    = qw + l16;
    const int   sw7   = l16 & 7;              // read-side swizzle key
    const int   h32   = wave * 32;            // this wave's key slice offset

    // Stage 128-key chunk [j0, j0+128): wave stages rows wave*32..wave*32+31.
    // j0+row <= nc*128-1 <= 2047: always inside this batch's K buffer; rows
    // >= len may be stale/uninit -> NaN-safe (masked before exp).
    auto stageK = [&](int buf, int j0) {
#pragma unroll
        for (int i = 0; i < 8; ++i) {
            const int c   = wave * 8 + i;           // 0..31
            const int row = c * 4 + quad;           // 0..127
            const int sb  = l16 ^ (row & 7);        // inverse-swizzled src blk
            lds16(Kbase + (size_t)(j0 + row) * DKK + sb * 8,
                  KB + buf * 16384 + c * 512);
        }
    };

    auto process = [&](int buf, int j0) {
        const int kbas = buf * 16384;
        // V for this wave's 32-key slice, straight from global/L2.  Guard:
        // slices entirely past len redirect to key 0 (avoid 0*NaN on
        // unwritten rows); P there is exactly 0 so the value is irrelevant.
        bf16x8 vf[8];
        {
            int jv = j0 + h32 + quad * 8;
            if (jv >= len) jv = 0;
#pragma unroll
            for (int nt = 0; nt < 8; ++nt)
                vf[nt] = *(const bf16x8*)(Vbase + (size_t)(nt*16 + l16) * SS + jv);
        }

        floatx4 st[2];
#pragma unroll
        for (int jt = 0; jt < 2; ++jt) {
            st[jt] = (floatx4){0.f,0.f,0.f,0.f};
#pragma unroll
            for (int cc = 0; cc < 4; ++cc) {
                bf16x8 kf = *(const bf16x8*)(
                    KB + kbas + (h32 + jt*16 + l16) * 128 + (((cc*4 + quad) ^ sw7) * 8));
                st[jt] = __builtin_amdgcn_mfma_f32_16x16x32_bf16(
                    kf, qfrag[cc], st[jt], 0, 0, 0);
            }
        }
        int pk[2][2];
#pragma unroll
        for (int jt = 0; jt < 2; ++jt) {
            float p[4];
#pragma unroll
            for (int rr = 0; rr < 4; ++rr) {
                const int j = j0 + h32 + jt*16 + quad*4 + rr;
                p[rr] = (j > iq || j >= len) ? 0.f : __expf(st[jt][rr] * scale - 8.f);
                lsum += p[rr];
            }
            pk[jt][0] = pack2(p[0], p[1]);
            pk[jt][1] = pack2(p[2], p[3]);
        }
        // C->A layout via cross-lane pull (verbatim R2..R9, harness-verified)
        const int a0 = (((quad & 1) << 5) + l16) << 2;
        const int a1 = a0 + 64;
        const int r00 = __builtin_amdgcn_ds_bpermute(a0, pk[0][0]);
        const int r01 = __builtin_amdgcn_ds_bpermute(a0, pk[0][1]);
        const int r02 = __builtin_amdgcn_ds_bpermute(a0, pk[1][0]);
        const int r03 = __builtin_amdgcn_ds_bpermute(a0, pk[1][1]);
        const int r10 = __builtin_amdgcn_ds_bpermute(a1, pk[0][0]);
        const int r11 = __builtin_amdgcn_ds_bpermute(a1, pk[0][1]);
        const int r12 = __builtin_amdgcn_ds_bpermute(a1, pk[1][0]);
        const int r13 = __builtin_amdgcn_ds_bpermute(a1, pk[1][1]);
        const bool hi = quad >= 2;
        union { intx4 i; bf16x8 h; } u;
        u.i = (intx4){ hi ? r02 : r00, hi ? r03 : r01,
                       hi ? r12 : r10, hi ? r13 : r11 };
#pragma unroll
        for (int nt = 0; nt < 8; ++nt)
            oacc[nt] = __builtin_amdgcn_mfma_f32_16x16x32_bf16(
                u.h, vf[nt], oacc[nt], 0, 0, 0);
    };

    stageK(0, 0);
    __syncthreads();
    for (int c = 0; c < nc; ++c) {
        const int cur = c & 1;
        if (c + 1 < nc) stageK(cur ^ 1, (c + 1) * 128);
        process(cur, c * 128);
        __syncthreads();
    }

    // quad-reduce lsum: every lane holds this wave's slice-total for q = l16
    lsum += __shfl_xor(lsum, 16, 64);
    lsum += __shfl_xor(lsum, 32, 64);

    // 4-way cross-wave reduce (overlay on KB after final barrier)
    float* Ored = (float*)KB;                 // 3 x [16][128] f32 = 24 KB
    float* Lred = (float*)KB + 3 * 2048;      // 3 x [16] f32
    if (wave != 0) {
#pragma unroll
        for (int nt = 0; nt < 8; ++nt)
#pragma unroll
            for (int rr = 0; rr < 4; ++rr)
                Ored[(wave-1)*2048 + (quad*4 + rr)*128 + nt*16 + l16] = oacc[nt][rr];
        if (lane < 16) Lred[(wave-1)*16 + l16] = lsum;
    }
    __syncthreads();
    if (wave == 0) {
        const float lt = lsum + Lred[l16] + Lred[16 + l16] + Lred[32 + l16];
        float inv[4];
#pragma unroll
        for (int rr = 0; rr < 4; ++rr)
            inv[rr] = 1.f / __shfl(lt, quad * 4 + rr, 64);
        // C/D layout: row(q) = quad*4+rr, col(dk) = nt*16+l16
#pragma unroll
        for (int nt = 0; nt < 8; ++nt)
#pragma unroll
            for (int rr = 0; rr < 4; ++rr) {
                const int idx = (quad*4 + rr)*128 + nt*16 + l16;
                out[(size_t)(b * SS + qw + quad*4 + rr) * DKK + nt*16 + l16] =
                    (oacc[nt][rr] + Ored[idx] + Ored[2048 + idx] + Ored[4096 + idx]) * inv[rr];
            }
    }
}

extern "C" void kernel_launch(void* const* d_in, const int* in_sizes, int n_in,
                              void* d_out, int out_size, void* d_ws, size_t ws_size,
                              hipStream_t stream) {
    const float* x   = (const float*)d_in[0];
    const float* ctx = (const float*)d_in[1];
    const float* Wq  = (const float*)d_in[2];
    const float* Wk  = (const float*)d_in[3];
    const float* Wv  = (const float*)d_in[4];
    const int* lengths = (const int*)d_in[5];
    float* out = (float*)d_out;

    char* ws = (char*)d_ws;
    __bf16* Wt = (__bf16*)ws;                          // 768 KB
    __bf16* Qb = (__bf16*)(ws + 786432);               // 4 MB
    __bf16* Kb = (__bf16*)(ws + 786432 + 4194304);     // 4 MB
    __bf16* Vt = (__bf16*)(ws + 786432 + 8388608);     // 4 MB (V^T)
    float*  Vm = (float*) (ws + 786432 + 12582912);    // 4 KB

    convw_kernel<<<dim3(64, 3), 256, 0, stream>>>(Wq, Wk, Wv, Wt);
    proj_kernel<<<512, 256, 0, stream>>>(x, ctx, Wt, lengths, Qb, Kb, Vt);
    vmean_kernel<<<64, 256, 0, stream>>>(Vt, lengths, Vm);
    attn_kernel<<<1024, 256, 0, stream>>>(Qb, Kb, Vt, lengths, Vm, out);
}